// Round 3
// baseline (119.443 us; speedup 1.0000x reference)
//
#include <hip/hip_runtime.h>

typedef __bf16 bf16x8 __attribute__((ext_vector_type(8)));
typedef float  f32x4  __attribute__((ext_vector_type(4)));

__device__ __forceinline__ unsigned short f2bf(float f) {
  unsigned u = __float_as_uint(f);
  u = u + 0x7fffu + ((u >> 16) & 1u);   // RNE
  return (unsigned short)(u >> 16);
}
__device__ __forceinline__ float bf2f(unsigned short h) {
  return __uint_as_float(((unsigned)h) << 16);
}

// K0: convert x (f32) -> xb (bf16), 8 elems/thread
__global__ __launch_bounds__(256) void cvt_bf16(
    const float* __restrict__ x, unsigned short* __restrict__ xb, int total8) {
  int i = blockIdx.x * 256 + threadIdx.x;
  if (i >= total8) return;
  const float4* p = (const float4*)(x + (size_t)i * 8);
  float4 a = p[0], b = p[1];
  union { unsigned short u[8]; uint4 v; } r;
  r.u[0] = f2bf(a.x); r.u[1] = f2bf(a.y); r.u[2] = f2bf(a.z); r.u[3] = f2bf(a.w);
  r.u[4] = f2bf(b.x); r.u[5] = f2bf(b.y); r.u[6] = f2bf(b.z); r.u[7] = f2bf(b.w);
  ((uint4*)xb)[i] = r.v;
}

// Fused: per block of 128 nodes — gather+mean straight into LDS feat tile
// (bf16), stage root features, then 16x16x32 bf16 MFMA epilogue.
// Wave = 32 consecutive nodes (concentrates Exp(16) degree variance).
template <bool BF>
__global__ __launch_bounds__(256, 4) void sage_fused(
    const float* __restrict__ x, const unsigned short* __restrict__ xb,
    const int* __restrict__ row, const int* __restrict__ colptr,
    const float* __restrict__ W, const float* __restrict__ bias,
    float* __restrict__ out, int N) {
  __shared__ unsigned short ft[128][136];   // [node][k], 34.8 KB
  int tid = threadIdx.x;
  int l = tid & 63, w = tid >> 6;
  int n0 = blockIdx.x * 128;
  int rows = N - n0; if (rows > 128) rows = 128;

#define LDX(r) (BF ? bf2f(xb[(size_t)(r) * 64 + l]) : x[(size_t)(r) * 64 + l])
  // ---- gather phase: lane = feature, 16 gathers in flight ----
  for (int i = 0; i < 32; ++i) {
    int node = n0 + w * 32 + i;
    float acc = 0.0f;
    int deg = 0;
    if (node < N) {
      int s = colptr[node], e = colptr[node + 1];
      deg = e - s;
      int t = s;
      for (; t + 16 <= e; t += 16) {
        int r0 = row[t], r1 = row[t+1], r2 = row[t+2], r3 = row[t+3];
        int r4 = row[t+4], r5 = row[t+5], r6 = row[t+6], r7 = row[t+7];
        int r8 = row[t+8], r9 = row[t+9], r10 = row[t+10], r11 = row[t+11];
        int r12 = row[t+12], r13 = row[t+13], r14 = row[t+14], r15 = row[t+15];
        float v0 = LDX(r0),  v1 = LDX(r1),  v2 = LDX(r2),  v3 = LDX(r3);
        float v4 = LDX(r4),  v5 = LDX(r5),  v6 = LDX(r6),  v7 = LDX(r7);
        float v8 = LDX(r8),  v9 = LDX(r9),  v10 = LDX(r10), v11 = LDX(r11);
        float v12 = LDX(r12), v13 = LDX(r13), v14 = LDX(r14), v15 = LDX(r15);
        acc += (((v0+v1)+(v2+v3)) + ((v4+v5)+(v6+v7)))
             + (((v8+v9)+(v10+v11)) + ((v12+v13)+(v14+v15)));
      }
      for (; t + 4 <= e; t += 4) {
        int r0 = row[t], r1 = row[t+1], r2 = row[t+2], r3 = row[t+3];
        float v0 = LDX(r0), v1 = LDX(r1), v2 = LDX(r2), v3 = LDX(r3);
        acc += (v0 + v1) + (v2 + v3);
      }
      for (; t < e; ++t) acc += LDX(row[t]);
    }
    float scale = (deg > 0) ? (1.0f / (float)deg) : 0.0f;
    ft[w * 32 + i][l] = f2bf(acc * scale);
  }
#undef LDX

  // ---- stage root-feature half: ft[n][64..127] ----
  #pragma unroll
  for (int it = 0; it < 4; ++it) {
    int flat = it * 2048 + tid * 8;
    int n = flat >> 6, k = flat & 63;
    uint4 v = make_uint4(0, 0, 0, 0);
    if (n < rows) {
      if (BF) {
        v = *(const uint4*)(xb + ((size_t)(n0 + n) * 64 + k));
      } else {
        const float4* p = (const float4*)(x + (size_t)(n0 + n) * 64 + k);
        float4 a = p[0], bb = p[1];
        union { unsigned short u[8]; uint4 vv; } r;
        r.u[0] = f2bf(a.x);  r.u[1] = f2bf(a.y);  r.u[2] = f2bf(a.z);  r.u[3] = f2bf(a.w);
        r.u[4] = f2bf(bb.x); r.u[5] = f2bf(bb.y); r.u[6] = f2bf(bb.z); r.u[7] = f2bf(bb.w);
        v = r.vv;
      }
    }
    *(uint4*)&ft[n][64 + k] = v;
  }
  __syncthreads();

  // ---- MFMA epilogue: wave w owns rows [w*32, w*32+32), all 64 cols ----
  int colr = l & 15, kg = l >> 4;
  f32x4 acc[2][4];
  #pragma unroll
  for (int c = 0; c < 4; ++c) {
    float bv = bias[c * 16 + colr];
    acc[0][c] = (f32x4){bv, bv, bv, bv};
    acc[1][c] = acc[0][c];
  }

  #pragma unroll
  for (int kq = 0; kq < 4; ++kq) {
    bf16x8 a0 = *(const bf16x8*)&ft[w * 32 + colr][kq * 32 + kg * 8];
    bf16x8 a1 = *(const bf16x8*)&ft[w * 32 + 16 + colr][kq * 32 + kg * 8];
    #pragma unroll
    for (int c = 0; c < 4; ++c) {
      // load W fragment just-in-time (keeps gather-phase VGPR low)
      const float* wp = W + (size_t)(c * 16 + colr) * 128 + kq * 32 + kg * 8;
      float4 wa = *(const float4*)wp;
      float4 wb = *(const float4*)(wp + 4);
      union { unsigned short u[8]; bf16x8 v; } r;
      r.u[0] = f2bf(wa.x); r.u[1] = f2bf(wa.y); r.u[2] = f2bf(wa.z); r.u[3] = f2bf(wa.w);
      r.u[4] = f2bf(wb.x); r.u[5] = f2bf(wb.y); r.u[6] = f2bf(wb.z); r.u[7] = f2bf(wb.w);
      acc[0][c] = __builtin_amdgcn_mfma_f32_16x16x32_bf16(a0, r.v, acc[0][c], 0, 0, 0);
      acc[1][c] = __builtin_amdgcn_mfma_f32_16x16x32_bf16(a1, r.v, acc[1][c], 0, 0, 0);
    }
  }

  // ---- store: C/D layout col=l&15, row=(l>>4)*4+r ----
  #pragma unroll
  for (int m = 0; m < 2; ++m) {
    int nodeb = n0 + w * 32 + m * 16 + kg * 4;
    #pragma unroll
    for (int c = 0; c < 4; ++c) {
      #pragma unroll
      for (int r = 0; r < 4; ++r) {
        int node = nodeb + r;
        if (node < N) out[(size_t)node * 64 + c * 16 + colr] = acc[m][c][r];
      }
    }
  }
}

extern "C" void kernel_launch(void* const* d_in, const int* in_sizes, int n_in,
                              void* d_out, int out_size, void* d_ws, size_t ws_size,
                              hipStream_t stream) {
  const float* x      = (const float*)d_in[0];
  const int*   row    = (const int*)d_in[1];
  const int*   colptr = (const int*)d_in[2];
  const float* W      = (const float*)d_in[3];
  const float* b      = (const float*)d_in[4];
  float* out = (float*)d_out;

  int N = in_sizes[0] / 64;
  bool bf = ws_size >= (size_t)N * 64 * sizeof(unsigned short);
  unsigned short* xb = (unsigned short*)d_ws;

  int nb = (N + 127) / 128;
  if (bf) {
    int total8 = N * 8;
    cvt_bf16<<<(total8 + 255) / 256, 256, 0, stream>>>(x, xb, total8);
    sage_fused<true><<<nb, 256, 0, stream>>>(x, xb, row, colptr, W, b, out, N);
  } else {
    sage_fused<false><<<nb, 256, 0, stream>>>(x, xb, row, colptr, W, b, out, N);
  }
}

// Round 5
// 95.824 us; speedup vs baseline: 1.2465x; 1.2465x over previous
//
#include <hip/hip_runtime.h>

typedef __bf16 bf16x8 __attribute__((ext_vector_type(8)));
typedef float  f32x4  __attribute__((ext_vector_type(4)));

__device__ __forceinline__ unsigned short f2bf(float f) {
  unsigned u = __float_as_uint(f);
  u = u + 0x7fffu + ((u >> 16) & 1u);   // RNE
  return (unsigned short)(u >> 16);
}
__device__ __forceinline__ float bf2f(unsigned short h) {
  return __uint_as_float(((unsigned)h) << 16);
}

// K0: convert x (f32) -> xb (bf16), 8 elems/thread
__global__ __launch_bounds__(256) void cvt_bf16(
    const float* __restrict__ x, unsigned short* __restrict__ xb, int total8) {
  int i = blockIdx.x * 256 + threadIdx.x;
  if (i >= total8) return;
  const float4* p = (const float4*)(x + (size_t)i * 8);
  float4 a = p[0], b = p[1];
  union { unsigned short u[8]; uint4 v; } r;
  r.u[0] = f2bf(a.x); r.u[1] = f2bf(a.y); r.u[2] = f2bf(a.z); r.u[3] = f2bf(a.w);
  r.u[4] = f2bf(b.x); r.u[5] = f2bf(b.y); r.u[6] = f2bf(b.z); r.u[7] = f2bf(b.w);
  ((uint4*)xb)[i] = r.v;
}

// K1: mean aggregation. 1 node per wave, lane = feature.
// Pipelined: 16 clamped gathers in flight; next batch's indices load while
// current batch's gathers are outstanding. AGGBF: write agg as bf16 to ws.
template <bool BF, bool AGGBF>
__global__ __launch_bounds__(256, 4) void agg_k(
    const float* __restrict__ x, const unsigned short* __restrict__ xb,
    const int* __restrict__ row, const int* __restrict__ colptr,
    float* __restrict__ aggf, unsigned short* __restrict__ aggb, int N) {
  int wid  = blockIdx.x * 4 + (threadIdx.x >> 6);
  int lane = threadIdx.x & 63;
  if (wid >= N) return;
  int s = colptr[wid], e = colptr[wid + 1];
  float acc = 0.0f;

#define LDX(r) (BF ? bf2f(xb[(size_t)(r) * 64 + lane]) : x[(size_t)(r) * 64 + lane])
  int t = s;
  if (t < e) {
    int ia[16];
    #pragma unroll
    for (int j = 0; j < 16; ++j) ia[j] = row[min(t + j, e - 1)];
    for (;;) {
      float g[16];
      #pragma unroll
      for (int j = 0; j < 16; ++j) g[j] = LDX(ia[j]);
      int lim = e - t;            // valid count this batch
      t += 16;
      bool more = t < e;
      if (more) {                 // prefetch next indices under gather latency
        #pragma unroll
        for (int j = 0; j < 16; ++j) ia[j] = row[min(t + j, e - 1)];
      }
      if (lim < 16) {
        #pragma unroll
        for (int j = 0; j < 16; ++j) g[j] = (j < lim) ? g[j] : 0.0f;
      }
      acc += (((g[0] + g[1]) + (g[2] + g[3])) + ((g[4] + g[5]) + (g[6] + g[7])))
           + (((g[8] + g[9]) + (g[10] + g[11])) + ((g[12] + g[13]) + (g[14] + g[15])));
      if (!more) break;
    }
  }
#undef LDX
  int deg = e - s;
  float r = (deg > 0) ? (acc / (float)deg) : 0.0f;
  if (AGGBF) aggb[(size_t)wid * 64 + lane] = f2bf(r);
  else       aggf[(size_t)wid * 64 + lane] = r;
}

// K2: out[n] = b + [agg|x] @ W^T via bf16 MFMA 16x16x32.
// AGGBF: agg half comes from bf16 ws buffer; else f32 in-place from out.
template <bool BF, bool AGGBF>
__global__ __launch_bounds__(256) void sage_mm(
    const float* __restrict__ x, const unsigned short* __restrict__ xb,
    const unsigned short* __restrict__ aggb,
    const float* __restrict__ W, const float* __restrict__ b,
    float* __restrict__ out, int N) {
  __shared__ unsigned short ft[128][136];
  int tid = threadIdx.x;
  int l = tid & 63, w = tid >> 6;
  int colr = l & 15, kg = l >> 4;
  int n0 = blockIdx.x * 128;
  int rows = N - n0; if (rows > 128) rows = 128;

  bf16x8 bfrag[4][4];
  float bias[4];
  #pragma unroll
  for (int c = 0; c < 4; ++c) {
    bias[c] = b[c * 16 + colr];
    #pragma unroll
    for (int kq = 0; kq < 4; ++kq) {
      const float* wp = W + (size_t)(c * 16 + colr) * 128 + kq * 32 + kg * 8;
      float4 wa = *(const float4*)wp;
      float4 wb = *(const float4*)(wp + 4);
      union { unsigned short u[8]; bf16x8 v; } r;
      r.u[0] = f2bf(wa.x); r.u[1] = f2bf(wa.y); r.u[2] = f2bf(wa.z); r.u[3] = f2bf(wa.w);
      r.u[4] = f2bf(wb.x); r.u[5] = f2bf(wb.y); r.u[6] = f2bf(wb.z); r.u[7] = f2bf(wb.w);
      bfrag[c][kq] = r.v;
    }
  }

  const float* aggsrcf = out + (size_t)n0 * 64;
  #pragma unroll
  for (int it = 0; it < 4; ++it) {
    int flat = it * 2048 + tid * 8;
    int n = flat >> 6, k = flat & 63;
    { // agg half -> ft[n][0..63]
      uint4 v = make_uint4(0, 0, 0, 0);
      if (n < rows) {
        if (AGGBF) {
          v = *(const uint4*)(aggb + ((size_t)(n0 + n) * 64 + k));
        } else {
          const float4* p = (const float4*)(aggsrcf + (size_t)n * 64 + k);
          float4 a = p[0], bb = p[1];
          union { unsigned short u[8]; uint4 vv; } r;
          r.u[0] = f2bf(a.x);  r.u[1] = f2bf(a.y);  r.u[2] = f2bf(a.z);  r.u[3] = f2bf(a.w);
          r.u[4] = f2bf(bb.x); r.u[5] = f2bf(bb.y); r.u[6] = f2bf(bb.z); r.u[7] = f2bf(bb.w);
          v = r.vv;
        }
      }
      *(uint4*)&ft[n][k] = v;
    }
    { // x half -> ft[n][64..127]
      uint4 v = make_uint4(0, 0, 0, 0);
      if (n < rows) {
        if (BF) {
          v = *(const uint4*)(xb + ((size_t)(n0 + n) * 64 + k));
        } else {
          const float4* p = (const float4*)(x + (size_t)(n0 + n) * 64 + k);
          float4 a = p[0], bb = p[1];
          union { unsigned short u[8]; uint4 vv; } r;
          r.u[0] = f2bf(a.x);  r.u[1] = f2bf(a.y);  r.u[2] = f2bf(a.z);  r.u[3] = f2bf(a.w);
          r.u[4] = f2bf(bb.x); r.u[5] = f2bf(bb.y); r.u[6] = f2bf(bb.z); r.u[7] = f2bf(bb.w);
          v = r.vv;
        }
      }
      *(uint4*)&ft[n][64 + k] = v;
    }
  }
  __syncthreads();

  f32x4 acc[2][4];
  #pragma unroll
  for (int c = 0; c < 4; ++c) {
    acc[0][c] = (f32x4){bias[c], bias[c], bias[c], bias[c]};
    acc[1][c] = acc[0][c];
  }

  #pragma unroll
  for (int kq = 0; kq < 4; ++kq) {
    bf16x8 a0 = *(const bf16x8*)&ft[w * 32 + colr][kq * 32 + kg * 8];
    bf16x8 a1 = *(const bf16x8*)&ft[w * 32 + 16 + colr][kq * 32 + kg * 8];
    #pragma unroll
    for (int c = 0; c < 4; ++c) {
      acc[0][c] = __builtin_amdgcn_mfma_f32_16x16x32_bf16(a0, bfrag[c][kq], acc[0][c], 0, 0, 0);
      acc[1][c] = __builtin_amdgcn_mfma_f32_16x16x32_bf16(a1, bfrag[c][kq], acc[1][c], 0, 0, 0);
    }
  }

  #pragma unroll
  for (int m = 0; m < 2; ++m) {
    int nodeb = n0 + w * 32 + m * 16 + kg * 4;
    #pragma unroll
    for (int c = 0; c < 4; ++c) {
      #pragma unroll
      for (int r = 0; r < 4; ++r) {
        int node = nodeb + r;
        if (node < N) out[(size_t)node * 64 + c * 16 + colr] = acc[m][c][r];
      }
    }
  }
}

extern "C" void kernel_launch(void* const* d_in, const int* in_sizes, int n_in,
                              void* d_out, int out_size, void* d_ws, size_t ws_size,
                              hipStream_t stream) {
  const float* x      = (const float*)d_in[0];
  const int*   row    = (const int*)d_in[1];
  const int*   colptr = (const int*)d_in[2];
  const float* W      = (const float*)d_in[3];
  const float* b      = (const float*)d_in[4];
  float* out = (float*)d_out;

  int N = in_sizes[0] / 64;
  size_t nb_bf = (size_t)N * 64 * 2;   // bf16 x copy
  unsigned short* xb = (unsigned short*)d_ws;
  unsigned short* xa = (unsigned short*)((char*)d_ws + nb_bf);  // bf16 agg

  int total8 = N * 8;
  int nbc = (total8 + 255) / 256;
  int nba = (N + 3) / 4;
  int nbm = (N + 127) / 128;

  if (ws_size >= 2 * nb_bf) {
    // bf16 gather + bf16 agg in ws (no f32 agg round-trip through out)
    cvt_bf16<<<nbc, 256, 0, stream>>>(x, xb, total8);
    agg_k<true, true><<<nba, 256, 0, stream>>>(x, xb, row, colptr, out, xa, N);
    sage_mm<true, true><<<nbm, 256, 0, stream>>>(x, xb, xa, W, b, out, N);
  } else if (ws_size >= nb_bf) {
    cvt_bf16<<<nbc, 256, 0, stream>>>(x, xb, total8);
    agg_k<true, false><<<nba, 256, 0, stream>>>(x, xb, row, colptr, out, xa, N);
    sage_mm<true, false><<<nbm, 256, 0, stream>>>(x, xb, xa, W, b, out, N);
  } else {
    agg_k<false, false><<<nba, 256, 0, stream>>>(x, xb, row, colptr, out, xa, N);
    sage_mm<false, false><<<nbm, 256, 0, stream>>>(x, xb, xa, W, b, out, N);
  }
}

// Round 6
// 75.788 us; speedup vs baseline: 1.5760x; 1.2644x over previous
//
#include <hip/hip_runtime.h>

typedef __bf16 bf16x8 __attribute__((ext_vector_type(8)));
typedef float  f32x4  __attribute__((ext_vector_type(4)));

__device__ __forceinline__ unsigned short f2bf(float f) {
  unsigned u = __float_as_uint(f);
  u = u + 0x7fffu + ((u >> 16) & 1u);   // RNE
  return (unsigned short)(u >> 16);
}
__device__ __forceinline__ float bf2f(unsigned short h) {
  return __uint_as_float(((unsigned)h) << 16);
}

// K0: convert x (f32) -> xb (bf16), 8 elems/thread
__global__ __launch_bounds__(256) void cvt_bf16(
    const float* __restrict__ x, unsigned short* __restrict__ xb, int total8) {
  int i = blockIdx.x * 256 + threadIdx.x;
  if (i >= total8) return;
  const float4* p = (const float4*)(x + (size_t)i * 8);
  float4 a = p[0], b = p[1];
  union { unsigned short u[8]; uint4 v; } r;
  r.u[0] = f2bf(a.x); r.u[1] = f2bf(a.y); r.u[2] = f2bf(a.z); r.u[3] = f2bf(a.w);
  r.u[4] = f2bf(b.x); r.u[5] = f2bf(b.y); r.u[6] = f2bf(b.z); r.u[7] = f2bf(b.w);
  ((uint4*)xb)[i] = r.v;
}

// K1: mean aggregation. 1 node per wave, lane = feature.
// Wave-uniform work scalarized: s/e via readfirstlane; a batch of 16 edge
// indices arrives via ONE vector load (lanes 0..15, replicated) and is
// distributed to SGPRs with v_readlane. Gather bases are SGPR + lane offset.
template <bool BF, bool AGGBF>
__global__ __launch_bounds__(256) void agg_k(
    const float* __restrict__ x, const unsigned short* __restrict__ xb,
    const int* __restrict__ row, const int* __restrict__ colptr,
    float* __restrict__ aggf, unsigned short* __restrict__ aggb, int N) {
  int wid  = blockIdx.x * 4 + (threadIdx.x >> 6);
  int lane = threadIdx.x & 63;
  if (wid >= N) return;
  int s = __builtin_amdgcn_readfirstlane(colptr[wid]);
  int e = __builtin_amdgcn_readfirstlane(colptr[wid + 1]);
  float acc = 0.0f;

  int t = s;
  if (t < e) {
    int li = lane & 15;
    int myidx = row[min(t + li, e - 1)];   // batch-16 indices in one load
    for (;;) {
      int lim  = e - t;
      int nt   = t + 16;
      bool more = nt < e;
      // distribute current indices to SGPRs
      int idx0  = __builtin_amdgcn_readlane(myidx, 0);
      int idx1  = __builtin_amdgcn_readlane(myidx, 1);
      int idx2  = __builtin_amdgcn_readlane(myidx, 2);
      int idx3  = __builtin_amdgcn_readlane(myidx, 3);
      int idx4  = __builtin_amdgcn_readlane(myidx, 4);
      int idx5  = __builtin_amdgcn_readlane(myidx, 5);
      int idx6  = __builtin_amdgcn_readlane(myidx, 6);
      int idx7  = __builtin_amdgcn_readlane(myidx, 7);
      int idx8  = __builtin_amdgcn_readlane(myidx, 8);
      int idx9  = __builtin_amdgcn_readlane(myidx, 9);
      int idx10 = __builtin_amdgcn_readlane(myidx, 10);
      int idx11 = __builtin_amdgcn_readlane(myidx, 11);
      int idx12 = __builtin_amdgcn_readlane(myidx, 12);
      int idx13 = __builtin_amdgcn_readlane(myidx, 13);
      int idx14 = __builtin_amdgcn_readlane(myidx, 14);
      int idx15 = __builtin_amdgcn_readlane(myidx, 15);
      // prefetch next batch's indices while gathers are outstanding
      if (more) myidx = row[min(nt + li, e - 1)];
      float g[16];
#define GATH(J, IDX)                                                         \
      g[J] = BF ? bf2f(xb[(size_t)(IDX) * 64 + lane])                        \
                : x[(size_t)(IDX) * 64 + lane];
      GATH(0, idx0)  GATH(1, idx1)  GATH(2, idx2)  GATH(3, idx3)
      GATH(4, idx4)  GATH(5, idx5)  GATH(6, idx6)  GATH(7, idx7)
      GATH(8, idx8)  GATH(9, idx9)  GATH(10, idx10) GATH(11, idx11)
      GATH(12, idx12) GATH(13, idx13) GATH(14, idx14) GATH(15, idx15)
#undef GATH
      if (lim < 16) {
        #pragma unroll
        for (int j = 0; j < 16; ++j) g[j] = (j < lim) ? g[j] : 0.0f;
      }
      acc += (((g[0] + g[1]) + (g[2] + g[3])) + ((g[4] + g[5]) + (g[6] + g[7])))
           + (((g[8] + g[9]) + (g[10] + g[11])) + ((g[12] + g[13]) + (g[14] + g[15])));
      if (!more) break;
      t = nt;
    }
  }
  int deg = e - s;
  float r = (deg > 0) ? (acc / (float)deg) : 0.0f;
  if (AGGBF) aggb[(size_t)wid * 64 + lane] = f2bf(r);
  else       aggf[(size_t)wid * 64 + lane] = r;
}

// K2: out[n] = b + [agg|x] @ W^T via bf16 MFMA 16x16x32.
// AGGBF: agg half comes from bf16 ws buffer; else f32 in-place from out.
template <bool BF, bool AGGBF>
__global__ __launch_bounds__(256) void sage_mm(
    const float* __restrict__ x, const unsigned short* __restrict__ xb,
    const unsigned short* __restrict__ aggb,
    const float* __restrict__ W, const float* __restrict__ b,
    float* __restrict__ out, int N) {
  __shared__ unsigned short ft[128][136];
  int tid = threadIdx.x;
  int l = tid & 63, w = tid >> 6;
  int colr = l & 15, kg = l >> 4;
  int n0 = blockIdx.x * 128;
  int rows = N - n0; if (rows > 128) rows = 128;

  bf16x8 bfrag[4][4];
  float bias[4];
  #pragma unroll
  for (int c = 0; c < 4; ++c) {
    bias[c] = b[c * 16 + colr];
    #pragma unroll
    for (int kq = 0; kq < 4; ++kq) {
      const float* wp = W + (size_t)(c * 16 + colr) * 128 + kq * 32 + kg * 8;
      float4 wa = *(const float4*)wp;
      float4 wb = *(const float4*)(wp + 4);
      union { unsigned short u[8]; bf16x8 v; } r;
      r.u[0] = f2bf(wa.x); r.u[1] = f2bf(wa.y); r.u[2] = f2bf(wa.z); r.u[3] = f2bf(wa.w);
      r.u[4] = f2bf(wb.x); r.u[5] = f2bf(wb.y); r.u[6] = f2bf(wb.z); r.u[7] = f2bf(wb.w);
      bfrag[c][kq] = r.v;
    }
  }

  const float* aggsrcf = out + (size_t)n0 * 64;
  #pragma unroll
  for (int it = 0; it < 4; ++it) {
    int flat = it * 2048 + tid * 8;
    int n = flat >> 6, k = flat & 63;
    { // agg half -> ft[n][0..63]
      uint4 v = make_uint4(0, 0, 0, 0);
      if (n < rows) {
        if (AGGBF) {
          v = *(const uint4*)(aggb + ((size_t)(n0 + n) * 64 + k));
        } else {
          const float4* p = (const float4*)(aggsrcf + (size_t)n * 64 + k);
          float4 a = p[0], bb = p[1];
          union { unsigned short u[8]; uint4 vv; } r;
          r.u[0] = f2bf(a.x);  r.u[1] = f2bf(a.y);  r.u[2] = f2bf(a.z);  r.u[3] = f2bf(a.w);
          r.u[4] = f2bf(bb.x); r.u[5] = f2bf(bb.y); r.u[6] = f2bf(bb.z); r.u[7] = f2bf(bb.w);
          v = r.vv;
        }
      }
      *(uint4*)&ft[n][k] = v;
    }
    { // x half -> ft[n][64..127]
      uint4 v = make_uint4(0, 0, 0, 0);
      if (n < rows) {
        if (BF) {
          v = *(const uint4*)(xb + ((size_t)(n0 + n) * 64 + k));
        } else {
          const float4* p = (const float4*)(x + (size_t)(n0 + n) * 64 + k);
          float4 a = p[0], bb = p[1];
          union { unsigned short u[8]; uint4 vv; } r;
          r.u[0] = f2bf(a.x);  r.u[1] = f2bf(a.y);  r.u[2] = f2bf(a.z);  r.u[3] = f2bf(a.w);
          r.u[4] = f2bf(bb.x); r.u[5] = f2bf(bb.y); r.u[6] = f2bf(bb.z); r.u[7] = f2bf(bb.w);
          v = r.vv;
        }
      }
      *(uint4*)&ft[n][64 + k] = v;
    }
  }
  __syncthreads();

  f32x4 acc[2][4];
  #pragma unroll
  for (int c = 0; c < 4; ++c) {
    acc[0][c] = (f32x4){bias[c], bias[c], bias[c], bias[c]};
    acc[1][c] = acc[0][c];
  }

  #pragma unroll
  for (int kq = 0; kq < 4; ++kq) {
    bf16x8 a0 = *(const bf16x8*)&ft[w * 32 + colr][kq * 32 + kg * 8];
    bf16x8 a1 = *(const bf16x8*)&ft[w * 32 + 16 + colr][kq * 32 + kg * 8];
    #pragma unroll
    for (int c = 0; c < 4; ++c) {
      acc[0][c] = __builtin_amdgcn_mfma_f32_16x16x32_bf16(a0, bfrag[c][kq], acc[0][c], 0, 0, 0);
      acc[1][c] = __builtin_amdgcn_mfma_f32_16x16x32_bf16(a1, bfrag[c][kq], acc[1][c], 0, 0, 0);
    }
  }

  #pragma unroll
  for (int m = 0; m < 2; ++m) {
    int nodeb = n0 + w * 32 + m * 16 + kg * 4;
    #pragma unroll
    for (int c = 0; c < 4; ++c) {
      #pragma unroll
      for (int r = 0; r < 4; ++r) {
        int node = nodeb + r;
        if (node < N) out[(size_t)node * 64 + c * 16 + colr] = acc[m][c][r];
      }
    }
  }
}

extern "C" void kernel_launch(void* const* d_in, const int* in_sizes, int n_in,
                              void* d_out, int out_size, void* d_ws, size_t ws_size,
                              hipStream_t stream) {
  const float* x      = (const float*)d_in[0];
  const int*   row    = (const int*)d_in[1];
  const int*   colptr = (const int*)d_in[2];
  const float* W      = (const float*)d_in[3];
  const float* b      = (const float*)d_in[4];
  float* out = (float*)d_out;

  int N = in_sizes[0] / 64;
  size_t nb_bf = (size_t)N * 64 * 2;   // bf16 x copy
  unsigned short* xb = (unsigned short*)d_ws;
  unsigned short* xa = (unsigned short*)((char*)d_ws + nb_bf);  // bf16 agg

  int total8 = N * 8;
  int nbc = (total8 + 255) / 256;
  int nba = (N + 3) / 4;
  int nbm = (N + 127) / 128;

  if (ws_size >= 2 * nb_bf) {
    cvt_bf16<<<nbc, 256, 0, stream>>>(x, xb, total8);
    agg_k<true, true><<<nba, 256, 0, stream>>>(x, xb, row, colptr, out, xa, N);
    sage_mm<true, true><<<nbm, 256, 0, stream>>>(x, xb, xa, W, b, out, N);
  } else if (ws_size >= nb_bf) {
    cvt_bf16<<<nbc, 256, 0, stream>>>(x, xb, total8);
    agg_k<true, false><<<nba, 256, 0, stream>>>(x, xb, row, colptr, out, xa, N);
    sage_mm<true, false><<<nbm, 256, 0, stream>>>(x, xb, xa, W, b, out, N);
  } else {
    agg_k<false, false><<<nba, 256, 0, stream>>>(x, xb, row, colptr, out, xa, N);
    sage_mm<false, false><<<nbm, 256, 0, stream>>>(x, xb, xa, W, b, out, N);
  }
}